// Round 23
// baseline (149.527 us; speedup 1.0000x reference)
//
#include <hip/hip_runtime.h>

#define B_   128
#define L_   196
#define ENC_ 2048
#define DEC_ 512
#define ATT_ 512
#define M_   (B_ * L_)   // 25088

typedef _Float16 f16x8 __attribute__((ext_vector_type(8)));
typedef __fp16   h16x2 __attribute__((ext_vector_type(2)));
typedef float    f32x4 __attribute__((ext_vector_type(4)));

// Raw barrier: order LDS ops (lgkmcnt) but do NOT drain vmcnt.
#define FENCE_LDS_BARRIER()                                        \
    do {                                                           \
        asm volatile("s_waitcnt lgkmcnt(0)" ::: "memory");         \
        __builtin_amdgcn_s_barrier();                              \
        __builtin_amdgcn_sched_barrier(0);                         \
    } while (0)

__device__ __forceinline__ void gload16(const _Float16* g, _Float16* l) {
    __builtin_amdgcn_global_load_lds(
        (const __attribute__((address_space(1))) void*)g,
        (__attribute__((address_space(3))) void*)l, 16, 0, 0);
}

// ---------------- ws layout ----------------
// [0,        262144)  dec_map f32 [128][512]
// [262144,  2359296)  WeTs2   f16 tiled [nt2=2][kt=64][k8=4][col=256] x f16x8
// [2359296, 2559904)  scores  f32 [2][25088]

// We [2048][512] fp32 -> WeTs2 tiled f16. Unit (nt2,kt,k8,col) holds
// We[kt*32+k8*8+j][nt2*256+col], j=0..7.
__global__ void wets2_kernel(const float* __restrict__ We, _Float16* __restrict__ WeTs) {
    int u = blockIdx.x * 256 + threadIdx.x;     // 131072 units
    int col = u & 255;
    int k8  = (u >> 8) & 3;
    int kt  = (u >> 10) & 63;
    int nt  = u >> 16;
    int n  = nt * 256 + col;
    int k0 = kt * 32 + k8 * 8;
    f16x8 h;
#pragma unroll
    for (int j = 0; j < 8; ++j) h[j] = (_Float16)We[(k0 + j) * ATT_ + n];
    *reinterpret_cast<f16x8*>(WeTs + (size_t)u * 8) = h;
}

__global__ void decmap_kernel(const float* __restrict__ dh, const float* __restrict__ Wd,
                              const float* __restrict__ bd, float* __restrict__ dec) {
    int b = blockIdx.x;       // 128
    int a = threadIdx.x;      // 512
    float acc = bd[a];
    const float* dhp = dh + b * DEC_;
#pragma unroll 8
    for (int k = 0; k < DEC_; ++k) acc += dhp[k] * Wd[k * ATT_ + a];
    dec[b * ATT_ + a] = acc;
}

// Fused GEMM: 256x256 tile, BK=32, 1024 threads = 16 waves (4 wm x 4 wn),
// wave tile 64x64, acc 16 frags = 64 regs. TLP thesis (R21=2/SIMD awful,
// R8=3/SIMD 2360cy/phase, every pipe <20%): the plateau is latency-bound and
// needs MORE WAVES/SIMD. launch_bounds(1024,4) -> 4 waves/SIMD, 16 waves/CU,
// 1 block/CU, grid 196 single round, A crosses L2 only 2x (410MB total).
// Register diet to fit the 128 cap: A single staging set (8 regs, T14
// load-early/write-late, R8 swizzle @256 rows); B one global_load_lds per
// thread per phase (0 regs). writeA's in-order reg-dep drains the earlier
// B-DMA for free -> lgkm-only fence, no explicit vmcnt. No setprio (m190).
__global__ __launch_bounds__(1024, 4)
void gemm_score_kernel(const float* __restrict__ enc,
                       const _Float16* __restrict__ WeTs,
                       const float* __restrict__ be,
                       const float* __restrict__ wa,
                       const float* __restrict__ dec,
                       float* __restrict__ scores) {
    __shared__ _Float16 As[2][8192];     // 16KB each: 1024 units (c8,row)
    __shared__ _Float16 Bs[2][8192];     // 16KB each: 1024 units (k8,col) linear
    __shared__ float red[4][256];

    // bijective XCD chunking for 196 blocks (q=24, r=4; m204):
    int bid = blockIdx.x;
    int xcd = bid & 7, kk = bid >> 3;
    int sid = (xcd < 4 ? xcd * 25 : 100 + (xcd - 4) * 24) + kk;
    int mtile = sid >> 1;                            // 0..97
    int nt2   = sid & 1;                             // 0..1

    int tid  = threadIdx.x;
    int lane = tid & 63, wid = tid >> 6;             // 16 waves
    int wm = wid >> 2, wn = wid & 3;                 // 4 x 4; wave = 64x64
    int l15 = lane & 15, lg = lane >> 4;

    // A staging: thread -> row = tid>>2 (0..255), c8 = tid&3, 8 fp32
    int arow = tid >> 2;
    int ac8  = tid & 3;
    const float* ag = enc + (size_t)(mtile * 256 + arow) * ENC_ + ac8 * 8;
    int wa0 = (ac8 * 256 + (arow ^ (2 * ac8))) * 8;  // swizzled unit (R8 pattern)

    // B DMA source: WeTs2 units (nt2, kt, unit=tid); per-kt 1024 units
    const _Float16* bsrc = WeTs + ((size_t)nt2 * 65536 + tid) * 8;

    // frag read half-offsets
    int afo = (lg * 256 + ((wm * 64 + l15) ^ (2 * lg))) * 8;    // + swizzle-consistent mi
    // note: row = wm*64 + mi*16 + l15; (row ^ 2lg) = (wm*64 + mi*16) + (l15 ^ 2lg)
    // since mi*16, wm*64 are multiples of 16 > XOR operand 2lg<8 acts on low 4 bits
    int axor = (l15 ^ (2 * lg)) - l15;               // delta applied once
    int bfo = (lg * 256 + wn * 64 + l15) * 8;        // + ni*128

    // single A staging register set (rule #20: fully static)
    f32x4 areg[2];

    f32x4 acc[4][4];
#pragma unroll
    for (int mi = 0; mi < 4; ++mi)
#pragma unroll
        for (int ni = 0; ni < 4; ++ni) acc[mi][ni] = (f32x4){0.f, 0.f, 0.f, 0.f};

    auto loadA = [&](int kt) {
        const float* a = ag + kt * 32;
        areg[0] = *reinterpret_cast<const f32x4*>(a);
        areg[1] = *reinterpret_cast<const f32x4*>(a + 4);
    };
    auto writeA = [&](int buf) {
        union { h16x2 h2[4]; f16x8 h8; } cv;
        cv.h2[0] = __builtin_amdgcn_cvt_pkrtz(areg[0][0], areg[0][1]);
        cv.h2[1] = __builtin_amdgcn_cvt_pkrtz(areg[0][2], areg[0][3]);
        cv.h2[2] = __builtin_amdgcn_cvt_pkrtz(areg[1][0], areg[1][1]);
        cv.h2[3] = __builtin_amdgcn_cvt_pkrtz(areg[1][2], areg[1][3]);
        *reinterpret_cast<f16x8*>(&As[buf][wa0]) = cv.h8;
    };
    auto dmab = [&](int buf, int kt) {
        gload16(bsrc + (size_t)kt * 8192, &Bs[buf][tid * 8]);
    };
    auto compute = [&](int buf) {
        const _Float16* Ap = As[buf];
        const _Float16* Bp = Bs[buf];
        f16x8 af[4], bf[4];
#pragma unroll
        for (int mi = 0; mi < 4; ++mi)
            af[mi] = *reinterpret_cast<const f16x8*>(
                Ap + (lg * 256 + wm * 64 + mi * 16 + l15 + axor) * 8);
#pragma unroll
        for (int ni = 0; ni < 4; ++ni)
            bf[ni] = *reinterpret_cast<const f16x8*>(Bp + bfo + ni * 128);
#pragma unroll
        for (int mi = 0; mi < 4; ++mi)
#pragma unroll
            for (int ni = 0; ni < 4; ++ni)
                acc[mi][ni] = __builtin_amdgcn_mfma_f32_16x16x32_f16(
                    af[mi], bf[ni], acc[mi][ni], 0, 0, 0);
    };

    // prologue: tile 0 -> As[0], Bs[0]
    dmab(0, 0);
    loadA(0);
    writeA(0);                                       // reg-dep drains loads+DMA
    FENCE_LDS_BARRIER();

    // phase k: DMA B(k+1)->Bs[(k+1)&1]; loadA(k+1) early; compute bufs k&1;
    // writeA(k+1)->As[(k+1)&1] late (reg-dep drains A loads AND the DMA,
    // in-order); lgkm fence. Buffers (k+1)&1 were last read phase k-1 ->
    // their reads drained at the k-1/k barrier -> WAR safe.
    for (int k2 = 0; k2 < 32; ++k2) {
        int k = k2 * 2;
        {
            int kn = k + 1;
            dmab(1, kn);
            loadA(kn);
            compute(0);
            writeA(1);
            FENCE_LDS_BARRIER();
        }
        {
            int kn = k + 2 < 64 ? k + 2 : 63;
            dmab(0, kn);
            loadA(kn);
            compute(1);
            writeA(0);
            FENCE_LDS_BARRIER();
        }
    }

    // Epilogue: x = acc + be[n] + dec[b][n]; rowsum += tanh(x)*wa[n]
    float rsum[4][4];
#pragma unroll
    for (int mi = 0; mi < 4; ++mi)
#pragma unroll
        for (int j = 0; j < 4; ++j) rsum[mi][j] = 0.f;

    int rb = mtile * 256 + wm * 64;
#pragma unroll
    for (int ni = 0; ni < 4; ++ni) {
        int n = nt2 * 256 + wn * 64 + ni * 16 + l15;
        float wav = wa[n];
        float bev = be[n];
#pragma unroll
        for (int mi = 0; mi < 4; ++mi) {
#pragma unroll
            for (int j = 0; j < 4; ++j) {
                int row = rb + mi * 16 + lg * 4 + j;    // C/D: col=lane&15, row=(lane>>4)*4+reg
                int b = row / L_;
                float x = acc[mi][ni][j] + bev + dec[b * ATT_ + n];
                float e = __expf(2.0f * x);
                float t = 1.0f - 2.0f / (e + 1.0f);     // tanh(x), inf-safe
                rsum[mi][j] += t * wav;
            }
        }
    }
#pragma unroll
    for (int mi = 0; mi < 4; ++mi) {
#pragma unroll
        for (int j = 0; j < 4; ++j) {
            float v = rsum[mi][j];
            v += __shfl_xor(v, 1);
            v += __shfl_xor(v, 2);
            v += __shfl_xor(v, 4);
            v += __shfl_xor(v, 8);
            if (l15 == 0) red[wn][wm * 64 + mi * 16 + lg * 4 + j] = v;
        }
    }
    __syncthreads();
    if (tid < 256)
        scores[(size_t)nt2 * M_ + mtile * 256 + tid] =
            red[0][tid] + red[1][tid] + red[2][tid] + red[3][tid];
}

// softmax over L per batch row; sums the 2 nt2 partials. ba cancels.
__global__ void softmax_kernel(const float* __restrict__ scores, float* __restrict__ alphas) {
    int b = blockIdx.x, t = threadIdx.x;     // 128 blocks x 256 threads
    int lane = t & 63, wid = t >> 6;
    __shared__ float red[4];
    float s = 0.f, val = -1e30f;
    if (t < L_) {
        int r = b * L_ + t;
        s = scores[r] + scores[M_ + r];
        val = s;
    }
    float m = val;
#pragma unroll
    for (int off = 1; off < 64; off <<= 1) m = fmaxf(m, __shfl_xor(m, off));
    if (lane == 0) red[wid] = m;
    __syncthreads();
    m = fmaxf(fmaxf(red[0], red[1]), fmaxf(red[2], red[3]));
    float e = (t < L_) ? __expf(s - m) : 0.f;
    float sum = e;
#pragma unroll
    for (int off = 1; off < 64; off <<= 1) sum += __shfl_xor(sum, off);
    __syncthreads();
    if (lane == 0) red[wid] = sum;
    __syncthreads();
    sum = red[0] + red[1] + red[2] + red[3];
    if (t < L_) alphas[b * L_ + t] = e / sum;
}

// context[b][e] = sum_l alphas[b][l] * enc[b][l][e]
__global__ void context_kernel(const float* __restrict__ enc, const float* __restrict__ alphas,
                               float* __restrict__ ctx) {
    int b = blockIdx.x >> 2;                  // 128 b x 4 e-chunks = 512 blocks
    int ec = blockIdx.x & 3;
    int e = ec * 512 + threadIdx.x * 2;
    const float* ep = enc + (size_t)b * L_ * ENC_ + e;
    const float* ap = alphas + b * L_;
    float ax = 0.f, ay = 0.f;
#pragma unroll 4
    for (int l = 0; l < L_; ++l) {
        float a = ap[l];
        float2 v = *reinterpret_cast<const float2*>(ep + (size_t)l * ENC_);
        ax += a * v.x;
        ay += a * v.y;
    }
    float2 r; r.x = ax; r.y = ay;
    *reinterpret_cast<float2*>(&ctx[b * ENC_ + e]) = r;
}

extern "C" void kernel_launch(void* const* d_in, const int* in_sizes, int n_in,
                              void* d_out, int out_size, void* d_ws, size_t ws_size,
                              hipStream_t stream) {
    const float* enc = (const float*)d_in[0];
    const float* dh  = (const float*)d_in[1];
    const float* We  = (const float*)d_in[2];
    const float* be  = (const float*)d_in[3];
    const float* Wd  = (const float*)d_in[4];
    const float* bd  = (const float*)d_in[5];
    const float* wa  = (const float*)d_in[6];
    // d_in[7] = ba: shifts all scores equally -> cancels in softmax, unused.

    float* out    = (float*)d_out;
    float* ctx    = out;               // [128][2048]
    float* alphas = out + B_ * ENC_;   // [128][196]

    char* ws = (char*)d_ws;
    float*    dec     = (float*)ws;                            // 256 KiB
    _Float16* WeTs2   = (_Float16*)(ws + 262144);              // 2 MiB
    float*    scores  = (float*)(ws + 2359296);                // 2 x 98 KiB

    hipLaunchKernelGGL(wets2_kernel,      dim3(512), dim3(256),  0, stream, We, WeTs2);
    hipLaunchKernelGGL(decmap_kernel,     dim3(128), dim3(512),  0, stream, dh, Wd, bd, dec);
    hipLaunchKernelGGL(gemm_score_kernel, dim3(196), dim3(1024), 0, stream, enc, WeTs2, be, wa, dec, scores);
    hipLaunchKernelGGL(softmax_kernel,    dim3(128), dim3(256),  0, stream, scores, alphas);
    hipLaunchKernelGGL(context_kernel,    dim3(512), dim3(256),  0, stream, enc, alphas, ctx);
}